// Round 11
// baseline (144.558 us; speedup 1.0000x reference)
//
#include <hip/hip_runtime.h>

// MPS classifier: logits[b,o] = (v/||v||)·cls[o] + log||v||,
//   v = head0(b) · M_1(b) · ... · M_783(b),  M_n = A_n + x[b,n]*(B_n - A_n).
// Chain associative; normalizations telescope.
//
// K1 (chunk_kernel): f16 chain math (v_pk_fma_f16), 2 lanes per sample,
//   L=16 sites/chunk. ALL chain state is typed `unsigned` (f16x2 bit
//   patterns); the packed-f16 asm takes i32 VGPR operands. This keeps the
//   allocator on pure i32 values -- r9/r10's _Float16 vector types + unions
//   defeated SROA and spilled (VGPR 60/32, scratch on the serial chain).
//   Weights fused-converted into LDS as f16 {A,D} dwords with exact x2.0
//   pre-scale (corrected via lbuf -= ns*ln2): 25 ds_read_b128/site/wave.
//   LDS-pipe floor ~24us.
// K2 (combine_kernel): f32 pbuf [c][b][100] contiguous, 64-thread blocks
//   (512 blocks -> all CUs), depth-8 prefetch ring, renorm every 8th chunk.

constexpr int Bsz  = 2048;
constexpr int Nn   = 784;
constexpr int NS   = 783;
constexpr int MAXL = 16;     // sites per chunk / LDS bound

// packed-f16 VOP3P on raw i32 registers. Semantics proven in r9/r10.
#define PKH_FMA(d, a, b, c) \
  asm("v_pk_fma_f16 %0, %1, %2, %3" : "=v"(d) : "v"(a), "v"(b), "v"(c))
// dst += m * s.lo (both halves use s's LOW half)
#define PKH_ACC_LO(d, m, s) \
  asm("v_pk_fma_f16 %0, %1, %2, %0 op_sel:[0,0,0] op_sel_hi:[1,0,1]" \
      : "+v"(d) : "v"(m), "v"(s))
// dst += m * s.hi
#define PKH_ACC_HI(d, m, s) \
  asm("v_pk_fma_f16 %0, %1, %2, %0 op_sel:[0,1,0] op_sel_hi:[1,1,1]" \
      : "+v"(d) : "v"(m), "v"(s))
// dst = m * s.lo
#define PKH_MUL_LO(d, m, s) \
  asm("v_pk_mul_f16 %0, %1, %2 op_sel:[0,0] op_sel_hi:[1,0]" \
      : "=v"(d) : "v"(m), "v"(s))

__device__ __forceinline__ unsigned short f2h_bits(float f) {
    union { _Float16 h; unsigned short u; } c;
    c.h = (_Float16)f;
    return c.u;
}
__device__ __forceinline__ float hlo(unsigned u) {
    union { unsigned short s; _Float16 h; } c;
    c.s = (unsigned short)(u & 0xffff);
    return (float)c.h;
}
__device__ __forceinline__ float hhi(unsigned u) {
    union { unsigned short s; _Float16 h; } c;
    c.s = (unsigned short)(u >> 16);
    return (float)c.h;
}

// dst(5x10) = src(5x10) * M(site); M blended row-pair at a time from LDS.
// ws = site base in s_w (100 dwords; pair s=(i*5+q) -> dwords 2s{A}, 2s+1{D})
__device__ __forceinline__ void site_step(const unsigned* __restrict__ ws,
                                          const unsigned x2,
                                          const unsigned (&src)[5][5],
                                          unsigned (&dst)[5][5]) {
#pragma unroll
    for (int ip = 0; ip < 5; ++ip) {
        unsigned m[10];   // m[2t],m[2t+1]: rows 2ip / 2ip+1, pair t
        const uint4* w4 = (const uint4*)(ws + ip * 20);
#pragma unroll
        for (int t = 0; t < 5; ++t) {
            const uint4 w = w4[t];
            PKH_FMA(m[2 * t],     w.y, x2, w.x);
            PKH_FMA(m[2 * t + 1], w.w, x2, w.z);
        }
#pragma unroll
        for (int r = 0; r < 5; ++r) {
            if (ip == 0) {
#pragma unroll
                for (int q = 0; q < 5; ++q) PKH_MUL_LO(dst[r][q], m[q], src[r][0]);
            } else {
#pragma unroll
                for (int q = 0; q < 5; ++q) PKH_ACC_LO(dst[r][q], m[q], src[r][ip]);
            }
#pragma unroll
            for (int q = 0; q < 5; ++q) PKH_ACC_HI(dst[r][q], m[5 + q], src[r][ip]);
        }
    }
}

// ---------------- K1: f16 chain, 2 lanes per sample ----------------------
__global__ __launch_bounds__(256, 2) void chunk_kernel(
    const float* __restrict__ x, const float* __restrict__ cores,
    float* __restrict__ pbuf, float* __restrict__ lbuf, int L) {
    __shared__ unsigned s_w[MAXL * 100];  // per-site f16 {A,D} dwords
    __shared__ float    s_x[128 * 17];    // x slice, stride 17

    const int c   = blockIdx.y;
    const int n0  = 1 + c * L;
    const int n1  = min(n0 + L, Nn);
    const int ns  = n1 - n0;
    const int tid = (int)threadIdx.x;
    const int b0  = (int)blockIdx.x * 128;

    // stage + convert weights (fused repack): pair e=(k,s), s=(i*5+q)
    for (int e = tid; e < ns * 50; e += 256) {
        const int k = e / 50, s = e - k * 50;
        const int i = s / 5, q = s - i * 5;
        const float* g = cores + (size_t)(n0 - 1 + k) * 200 + i * 20 + 2 * q;
        const float a0 = g[0], a1 = g[1], bb0 = g[10], bb1 = g[11];
        const unsigned A = ((unsigned)f2h_bits(2.f * a1) << 16) | f2h_bits(2.f * a0);
        const unsigned D = ((unsigned)f2h_bits(2.f * (bb1 - a1)) << 16) |
                           f2h_bits(2.f * (bb0 - a0));
        s_w[k * 100 + 2 * s]     = A;
        s_w[k * 100 + 2 * s + 1] = D;
    }
    // stage x slice (coalesced 16-wide)
    for (int e = tid; e < 128 * 16; e += 256) {
        const int bl = e >> 4, k = e & 15;
        if (k < ns) s_x[bl * 17 + k] = x[(size_t)(b0 + bl) * Nn + n0 + k];
    }
    __syncthreads();

    const int h = tid & 1;              // row-half owner
    const int u = tid >> 1;             // sample slot 0..127
    const int b = b0 + u;
    const float* __restrict__ xs = s_x + u * 17;

    unsigned p[5][5], q2[5][5];
    {   // first site: P = 2*M (rows 5h..5h+4)
        const unsigned short xb = f2h_bits(xs[0]);
        const unsigned x2 = ((unsigned)xb << 16) | xb;
#pragma unroll
        for (int r = 0; r < 5; ++r)
#pragma unroll
            for (int q = 0; q < 5; ++q) {
                const unsigned A = s_w[(5 * h + r) * 10 + 2 * q];
                const unsigned D = s_w[(5 * h + r) * 10 + 2 * q + 1];
                PKH_FMA(p[r][q], D, x2, A);
            }
    }
    int k = 1;
    while (k + 1 < ns) {        // ping-pong pairs, no copies
        {
            const unsigned short xb = f2h_bits(xs[k]);
            site_step(s_w + k * 100, ((unsigned)xb << 16) | xb, p, q2);
        }
        {
            const unsigned short xb = f2h_bits(xs[k + 1]);
            site_step(s_w + (k + 1) * 100, ((unsigned)xb << 16) | xb, q2, p);
        }
        k += 2;
    }
    if (k < ns) {               // odd-position tail site
        const unsigned short xb = f2h_bits(xs[k]);
        site_step(s_w + k * 100, ((unsigned)xb << 16) | xb, p, q2);
#pragma unroll
        for (int r = 0; r < 5; ++r)
#pragma unroll
            for (int q = 0; q < 5; ++q) p[r][q] = q2[r][q];
    }

    // Frobenius renorm (f32 accumulate, pair-reduce across the 2 lanes);
    // correct the 2^ns pre-scale in lbuf.
    float ss = 0.f;
#pragma unroll
    for (int r = 0; r < 5; ++r)
#pragma unroll
        for (int q = 0; q < 5; ++q) {
            const float lo = hlo(p[r][q]), hi = hhi(p[r][q]);
            ss = fmaf(lo, lo, ss);
            ss = fmaf(hi, hi, ss);
        }
    ss += __shfl_xor(ss, 1);
    ss = fmaxf(ss, 1e-30f);
    const float rin = rsqrtf(ss);
    if (h == 0)
        lbuf[(size_t)c * Bsz + b] = 0.5f * __logf(ss) - (float)ns * 0.69314718056f;

    // store f32, per-sample CONTIGUOUS 100-float block
    float* dst = pbuf + ((size_t)c * Bsz + b) * 100;
#pragma unroll
    for (int r = 0; r < 5; ++r)
#pragma unroll
        for (int q = 0; q < 5; ++q) {
            float2 v;
            v.x = hlo(p[r][q]) * rin;
            v.y = hhi(p[r][q]) * rin;
            *(float2*)(dst + (5 * h + r) * 10 + 2 * q) = v;
        }
}

// ---------------- K2: combine chunks + logits (16 lanes per sample) --------
// 64-thread blocks, 4 samples each -> 512 blocks (all CUs active).
__global__ __launch_bounds__(64, 8) void combine_kernel(
    const float* __restrict__ x, const float* __restrict__ core0,
    const float* __restrict__ cls, const float* __restrict__ pbuf,
    const float* __restrict__ lbuf, float* __restrict__ out, int C) {
    const int tid   = (int)threadIdx.x;
    const int j     = tid & 15;
    const int jj    = (j < 10) ? j : 9;
    const int gbase = tid & 48;
    const int b     = blockIdx.x * 4 + (tid >> 4);

    float v[10];
    const float x0 = x[(size_t)b * Nn];
#pragma unroll
    for (int i = 0; i < 10; ++i) {
        const float c0 = core0[i], c1 = core0[10 + i];
        v[i] = fmaf(x0, c1 - c0, c0);
    }

    // depth-8 prefetch ring, statically indexed; per-chunk data contiguous
    float w[8][10];
#pragma unroll
    for (int k8 = 0; k8 < 8; ++k8) {
        if (k8 < C) {
            const float* pn = pbuf + ((size_t)k8 * Bsz + b) * 100 + jj;
#pragma unroll
            for (int i = 0; i < 10; ++i) w[k8][i] = pn[i * 10];
        }
    }

    float llog = 0.f;
    for (int cg = 0; cg < C; cg += 8) {
#pragma unroll
        for (int k8 = 0; k8 < 8; ++k8) {
            const int c = cg + k8;
            if (c >= C) break;
            float acc = 0.f;
#pragma unroll
            for (int i = 0; i < 10; ++i) acc = fmaf(v[i], w[k8][i], acc);
            if (j >= 10) acc = 0.f;
            llog += lbuf[(size_t)c * Bsz + b];
            if (k8 == 7 || c == C - 1) {   // deferred renorm
                float s = acc * acc;
                s += __shfl_xor(s, 1);
                s += __shfl_xor(s, 2);
                s += __shfl_xor(s, 4);
                s += __shfl_xor(s, 8);
                s = fmaxf(s, 1e-30f);
                llog += 0.5f * __logf(s);
                acc *= rsqrtf(s);
            }
#pragma unroll
            for (int i = 0; i < 10; ++i) v[i] = __shfl(acc, gbase + i);
            if (c + 8 < C) {               // refill the slot just consumed
                const float* pn = pbuf + ((size_t)(c + 8) * Bsz + b) * 100 + jj;
#pragma unroll
                for (int i = 0; i < 10; ++i) w[k8][i] = pn[i * 10];
            }
        }
    }

    if (j < 10) {
        float acc = llog;
#pragma unroll
        for (int i = 0; i < 10; ++i) acc = fmaf(v[i], cls[j * 10 + i], acc);
        out[(size_t)b * 10 + j] = acc;
    }
}

// ---------------- launch ----------------
extern "C" void kernel_launch(void* const* d_in, const int* in_sizes, int n_in,
                              void* d_out, int out_size, void* d_ws, size_t ws_size,
                              hipStream_t stream) {
    const float* x     = (const float*)d_in[0];
    const float* core0 = (const float*)d_in[1];
    const float* cores = (const float*)d_in[2];
    const float* cls   = (const float*)d_in[3];
    float* out = (float*)d_out;

    int L = MAXL;                              // 16 sites/chunk
    int C = (NS + L - 1) / L;                  // 49
    float* pbuf = (float*)d_ws;                // C*Bsz*100 f32 = 40.1 MB
    float* lbuf = pbuf + (size_t)C * 100 * Bsz;

    hipLaunchKernelGGL(chunk_kernel, dim3(Bsz / 128, C), dim3(256),
                       0, stream, x, cores, pbuf, lbuf, L);
    hipLaunchKernelGGL(combine_kernel, dim3(Bsz / 4), dim3(64),
                       0, stream, x, core0, cls, pbuf, lbuf, out, C);
}

// Round 12
// 83.913 us; speedup vs baseline: 1.7227x; 1.7227x over previous
//
#include <hip/hip_runtime.h>

// MPS classifier: logits[b,o] = (v/||v||)·cls[o] + log||v||,
//   v = head0(b) · M_1(b) · ... · M_783(b),  M_n = A_n + x[b,n]*(B_n - A_n).
// Chain associative; normalizations telescope.
//
// K1 (chunk_kernel): f16 chain (v_pk_fma_f16 on raw `unsigned` f16x2 bit
//   patterns -- the typing that finally built clean in r11), ONE SAMPLE PER
//   LANE (64 samples/wave): halves wave count vs the 2-lane split, so the
//   LDS broadcast pipe (25 ds_read_b128/site/wave @ ~12cy) drops to ~12us,
//   balanced against ~11us of VALU. State p/q ping-pong = 110 live i32 --
//   under the 256-VGPR cap of __launch_bounds__(256,2).
//   Weights fused-converted into LDS with exact x2.0 pre-scale (corrected
//   via lbuf -= ns*ln2). L=16 sites/chunk, C=49.
// K2 (combine_kernel): r6's PROVEN geometry: 16 samples per 256-thread
//   block (launch_bounds(256,2) -> ring fits in regs; r11's 64-thread
//   launch_bounds(64,8) capped VGPR at 64 and spilled the ring = 95us).
//   f32 pbuf [c][b][100] contiguous, depth-8 prefetch ring, renorm every
//   8th chunk.

constexpr int Bsz  = 2048;
constexpr int Nn   = 784;
constexpr int NS   = 783;
constexpr int MAXL = 16;     // sites per chunk

// packed-f16 VOP3P on raw i32 registers (semantics proven r9-r11).
#define PKH_FMA(d, a, b, c) \
  asm("v_pk_fma_f16 %0, %1, %2, %3" : "=v"(d) : "v"(a), "v"(b), "v"(c))
#define PKH_ACC_LO(d, m, s) \
  asm("v_pk_fma_f16 %0, %1, %2, %0 op_sel:[0,0,0] op_sel_hi:[1,0,1]" \
      : "+v"(d) : "v"(m), "v"(s))
#define PKH_ACC_HI(d, m, s) \
  asm("v_pk_fma_f16 %0, %1, %2, %0 op_sel:[0,1,0] op_sel_hi:[1,1,1]" \
      : "+v"(d) : "v"(m), "v"(s))
#define PKH_MUL_LO(d, m, s) \
  asm("v_pk_mul_f16 %0, %1, %2 op_sel:[0,0] op_sel_hi:[1,0]" \
      : "=v"(d) : "v"(m), "v"(s))

__device__ __forceinline__ unsigned short f2h_bits(float f) {
    union { _Float16 h; unsigned short u; } c;
    c.h = (_Float16)f;
    return c.u;
}
__device__ __forceinline__ float hlo(unsigned u) {
    union { unsigned short s; _Float16 h; } c;
    c.s = (unsigned short)(u & 0xffff);
    return (float)c.h;
}
__device__ __forceinline__ float hhi(unsigned u) {
    union { unsigned short s; _Float16 h; } c;
    c.s = (unsigned short)(u >> 16);
    return (float)c.h;
}

// dst(10x10) = src(10x10) * M(site); M blended row-pair at a time from LDS.
// ws = site base in s_w (100 dwords; pair s=(i*5+q) -> dwords 2s{A}, 2s+1{D})
__device__ __forceinline__ void site_step(const unsigned* __restrict__ ws,
                                          const unsigned x2,
                                          const unsigned (&src)[10][5],
                                          unsigned (&dst)[10][5]) {
#pragma unroll
    for (int ip = 0; ip < 5; ++ip) {
        unsigned m[10];   // m[2t],m[2t+1]: M rows 2ip / 2ip+1, pair t
        const uint4* w4 = (const uint4*)(ws + ip * 20);
#pragma unroll
        for (int t = 0; t < 5; ++t) {
            const uint4 w = w4[t];
            PKH_FMA(m[2 * t],     w.y, x2, w.x);
            PKH_FMA(m[2 * t + 1], w.w, x2, w.z);
        }
#pragma unroll
        for (int r = 0; r < 10; ++r) {
            if (ip == 0) {
#pragma unroll
                for (int q = 0; q < 5; ++q) PKH_MUL_LO(dst[r][q], m[q], src[r][0]);
            } else {
#pragma unroll
                for (int q = 0; q < 5; ++q) PKH_ACC_LO(dst[r][q], m[q], src[r][ip]);
            }
#pragma unroll
            for (int q = 0; q < 5; ++q) PKH_ACC_HI(dst[r][q], m[5 + q], src[r][ip]);
        }
    }
}

// ---------------- K1: f16 chain, ONE sample per lane ----------------------
__global__ __launch_bounds__(256, 2) void chunk_kernel(
    const float* __restrict__ x, const float* __restrict__ cores,
    float* __restrict__ pbuf, float* __restrict__ lbuf, int L) {
    __shared__ unsigned s_w[MAXL * 100];  // per-site f16 {A,D} dwords
    __shared__ float    s_x[256 * 17];    // x slice, stride 17

    const int c   = blockIdx.y;
    const int n0  = 1 + c * L;
    const int n1  = min(n0 + L, Nn);
    const int ns  = n1 - n0;
    const int tid = (int)threadIdx.x;
    const int b0  = (int)blockIdx.x * 256;
    const int b   = b0 + tid;

    // stage + convert weights (fused repack): pair e=(k,s), s=(i*5+q)
    for (int e = tid; e < ns * 50; e += 256) {
        const int k = e / 50, s = e - k * 50;
        const int i = s / 5, q = s - i * 5;
        const float* g = cores + (size_t)(n0 - 1 + k) * 200 + i * 20 + 2 * q;
        const float a0 = g[0], a1 = g[1], bb0 = g[10], bb1 = g[11];
        const unsigned A = ((unsigned)f2h_bits(2.f * a1) << 16) | f2h_bits(2.f * a0);
        const unsigned D = ((unsigned)f2h_bits(2.f * (bb1 - a1)) << 16) |
                           f2h_bits(2.f * (bb0 - a0));
        s_w[k * 100 + 2 * s]     = A;
        s_w[k * 100 + 2 * s + 1] = D;
    }
    // stage x slice (coalesced 16-wide)
    for (int e = tid; e < 256 * 16; e += 256) {
        const int bl = e >> 4, k = e & 15;
        if (k < ns) s_x[bl * 17 + k] = x[(size_t)(b0 + bl) * Nn + n0 + k];
    }
    __syncthreads();

    const float* __restrict__ xs = s_x + tid * 17;

    unsigned p[10][5], q2[10][5];
    {   // first site: P = 2*M
        const unsigned short xb = f2h_bits(xs[0]);
        const unsigned x2 = ((unsigned)xb << 16) | xb;
#pragma unroll
        for (int r = 0; r < 10; ++r)
#pragma unroll
            for (int q = 0; q < 5; ++q) {
                const unsigned A = s_w[r * 10 + 2 * q];
                const unsigned D = s_w[r * 10 + 2 * q + 1];
                PKH_FMA(p[r][q], D, x2, A);
            }
    }
    int k = 1;
    while (k + 1 < ns) {        // ping-pong pairs, no copies
        {
            const unsigned short xb = f2h_bits(xs[k]);
            site_step(s_w + k * 100, ((unsigned)xb << 16) | xb, p, q2);
        }
        {
            const unsigned short xb = f2h_bits(xs[k + 1]);
            site_step(s_w + (k + 1) * 100, ((unsigned)xb << 16) | xb, q2, p);
        }
        k += 2;
    }
    if (k < ns) {               // odd-position tail site
        const unsigned short xb = f2h_bits(xs[k]);
        site_step(s_w + k * 100, ((unsigned)xb << 16) | xb, p, q2);
#pragma unroll
        for (int r = 0; r < 10; ++r)
#pragma unroll
            for (int q = 0; q < 5; ++q) p[r][q] = q2[r][q];
    }

    // Frobenius renorm (f32 accumulate, in-lane); correct 2^ns pre-scale.
    float ss = 0.f;
#pragma unroll
    for (int r = 0; r < 10; ++r)
#pragma unroll
        for (int q = 0; q < 5; ++q) {
            const float lo = hlo(p[r][q]), hi = hhi(p[r][q]);
            ss = fmaf(lo, lo, ss);
            ss = fmaf(hi, hi, ss);
        }
    ss = fmaxf(ss, 1e-30f);
    const float rin = rsqrtf(ss);
    lbuf[(size_t)c * Bsz + b] = 0.5f * __logf(ss) - (float)ns * 0.69314718056f;

    // store f32, per-sample CONTIGUOUS 100-float block
    float* dst = pbuf + ((size_t)c * Bsz + b) * 100;
#pragma unroll
    for (int r = 0; r < 10; ++r)
#pragma unroll
        for (int q = 0; q < 5; ++q) {
            float2 v;
            v.x = hlo(p[r][q]) * rin;
            v.y = hhi(p[r][q]) * rin;
            *(float2*)(dst + r * 10 + 2 * q) = v;
        }
}

// ---------------- K2: combine chunks + logits (16 lanes per sample) --------
// r6's proven geometry: 16 samples per 256-thread block, grid = Bsz/16.
__global__ __launch_bounds__(256, 2) void combine_kernel(
    const float* __restrict__ x, const float* __restrict__ core0,
    const float* __restrict__ cls, const float* __restrict__ pbuf,
    const float* __restrict__ lbuf, float* __restrict__ out, int C) {
    const int tid   = (int)threadIdx.x;
    const int j     = tid & 15;
    const int jj    = (j < 10) ? j : 9;
    const int gbase = tid & 48;
    const int b     = blockIdx.x * 16 + (tid >> 4);

    float v[10];
    const float x0 = x[(size_t)b * Nn];
#pragma unroll
    for (int i = 0; i < 10; ++i) {
        const float c0 = core0[i], c1 = core0[10 + i];
        v[i] = fmaf(x0, c1 - c0, c0);
    }

    // depth-8 prefetch ring, statically indexed; per-chunk data contiguous
    float w[8][10];
#pragma unroll
    for (int k8 = 0; k8 < 8; ++k8) {
        if (k8 < C) {
            const float* pn = pbuf + ((size_t)k8 * Bsz + b) * 100 + jj;
#pragma unroll
            for (int i = 0; i < 10; ++i) w[k8][i] = pn[i * 10];
        }
    }

    float llog = 0.f;
    for (int cg = 0; cg < C; cg += 8) {
#pragma unroll
        for (int k8 = 0; k8 < 8; ++k8) {
            const int c = cg + k8;
            if (c >= C) break;
            float acc = 0.f;
#pragma unroll
            for (int i = 0; i < 10; ++i) acc = fmaf(v[i], w[k8][i], acc);
            if (j >= 10) acc = 0.f;
            llog += lbuf[(size_t)c * Bsz + b];
            if (k8 == 7 || c == C - 1) {   // deferred renorm
                float s = acc * acc;
                s += __shfl_xor(s, 1);
                s += __shfl_xor(s, 2);
                s += __shfl_xor(s, 4);
                s += __shfl_xor(s, 8);
                s = fmaxf(s, 1e-30f);
                llog += 0.5f * __logf(s);
                acc *= rsqrtf(s);
            }
#pragma unroll
            for (int i = 0; i < 10; ++i) v[i] = __shfl(acc, gbase + i);
            if (c + 8 < C) {               // refill the slot just consumed
                const float* pn = pbuf + ((size_t)(c + 8) * Bsz + b) * 100 + jj;
#pragma unroll
                for (int i = 0; i < 10; ++i) w[k8][i] = pn[i * 10];
            }
        }
    }

    if (j < 10) {
        float acc = llog;
#pragma unroll
        for (int i = 0; i < 10; ++i) acc = fmaf(v[i], cls[j * 10 + i], acc);
        out[(size_t)b * 10 + j] = acc;
    }
}

// ---------------- launch ----------------
extern "C" void kernel_launch(void* const* d_in, const int* in_sizes, int n_in,
                              void* d_out, int out_size, void* d_ws, size_t ws_size,
                              hipStream_t stream) {
    const float* x     = (const float*)d_in[0];
    const float* core0 = (const float*)d_in[1];
    const float* cores = (const float*)d_in[2];
    const float* cls   = (const float*)d_in[3];
    float* out = (float*)d_out;

    int L = MAXL;                              // 16 sites/chunk
    int C = (NS + L - 1) / L;                  // 49
    float* pbuf = (float*)d_ws;                // C*Bsz*100 f32 = 40.1 MB
    float* lbuf = pbuf + (size_t)C * 100 * Bsz;

    hipLaunchKernelGGL(chunk_kernel, dim3(Bsz / 256, C), dim3(256),
                       0, stream, x, cores, pbuf, lbuf, L);
    hipLaunchKernelGGL(combine_kernel, dim3(Bsz / 16), dim3(256),
                       0, stream, x, core0, cls, pbuf, lbuf, out, C);
}